// Round 11
// baseline (205.007 us; speedup 1.0000x reference)
//
#include <hip/hip_runtime.h>

typedef unsigned short u16;
typedef u16   u16x8 __attribute__((ext_vector_type(8)));
typedef __bf16 bf16x8 __attribute__((ext_vector_type(8)));
typedef float f32x4 __attribute__((ext_vector_type(4)));
typedef float f32x2 __attribute__((ext_vector_type(2)));
typedef _Float16 f16x4 __attribute__((ext_vector_type(4)));
typedef _Float16 f16x8 __attribute__((ext_vector_type(8)));
typedef unsigned u32x2 __attribute__((ext_vector_type(2)));

__device__ __forceinline__ u16 f2b(float f){ __bf16 h=(__bf16)f; return __builtin_bit_cast(u16,h); }

__device__ __forceinline__ f32x4 mfma16(u16x8 a, u16x8 b, f32x4 c){
  return __builtin_amdgcn_mfma_f32_16x16x32_bf16(
      __builtin_bit_cast(bf16x8,a), __builtin_bit_cast(bf16x8,b), c, 0,0,0);
}

__device__ __forceinline__ void gl2lds16(const u16* g, u16* l){
  __builtin_amdgcn_global_load_lds((const __attribute__((address_space(1))) void*)g,
                                   (__attribute__((address_space(3))) void*)l, 16, 0, 0);
}

// ---------------- LayerNorm: fp32 [4096,1024] -> bf16 xn ----------------
__global__ __launch_bounds__(256) void ln_kernel(const float* __restrict__ x,
                                                 const float* __restrict__ gamma,
                                                 const float* __restrict__ beta,
                                                 u16* __restrict__ xn){
  const int row = blockIdx.x, t = threadIdx.x;
  const float4 v = ((const float4*)(x + (size_t)row*1024))[t];
  float s  = v.x+v.y+v.z+v.w;
  float sq = v.x*v.x+v.y*v.y+v.z*v.z+v.w*v.w;
  for (int m=1;m<64;m<<=1){ s += __shfl_xor(s,m); sq += __shfl_xor(sq,m); }
  __shared__ float red[8];
  const int w=t>>6, l=t&63;
  if(l==0){ red[w]=s; red[4+w]=sq; }
  __syncthreads();
  const float S  = red[0]+red[1]+red[2]+red[3];
  const float SQ = red[4]+red[5]+red[6]+red[7];
  const float mu = S*(1.f/1024.f);
  const float var= SQ*(1.f/1024.f)-mu*mu;
  const float rs = rsqrtf(var+1e-5f);
  const float4 g4=((const float4*)gamma)[t], b4=((const float4*)beta)[t];
  u16 o0=f2b((v.x-mu)*rs*g4.x+b4.x);
  u16 o1=f2b((v.y-mu)*rs*g4.y+b4.y);
  u16 o2=f2b((v.z-mu)*rs*g4.z+b4.z);
  u16 o3=f2b((v.w-mu)*rs*g4.w+b4.w);
  uint2 p; p.x=(unsigned)o0|((unsigned)o1<<16); p.y=(unsigned)o2|((unsigned)o3<<16);
  ((uint2*)(xn + (size_t)row*1024))[t]=p;
}

// ------- transpose-convert all 3 weights fp32 [R][C] -> bf16 [C][R] -------
__global__ __launch_bounds__(256) void wtrans_all_kernel(const float* __restrict__ wq,
    const float* __restrict__ wkv, const float* __restrict__ wout,
    u16* __restrict__ wqkvt, u16* __restrict__ woutt){
  __shared__ float tile[64][65];
  const int bx=blockIdx.x, t=threadIdx.x;
  const float* in; u16* out; int C, cxx;
  if(bx<16){ in=wq;  out=wqkvt;           C=1024; cxx=bx; }
  else if(bx<48){ in=wkv; out=wqkvt+1024*1024; C=2048; cxx=bx-16; }
  else { in=wout; out=woutt;             C=1024; cxx=bx-48; }
  const int R=1024;
  const int c0=cxx*64, r0=blockIdx.y*64;
  {
    const int r=t>>2, cc=t&3;
    const float* gp = in + (size_t)(r0+r)*C + c0 + cc*16;
    #pragma unroll
    for(int i=0;i<4;i++){
      float4 f=((const float4*)gp)[i];
      tile[r][cc*16+i*4+0]=f.x; tile[r][cc*16+i*4+1]=f.y;
      tile[r][cc*16+i*4+2]=f.z; tile[r][cc*16+i*4+3]=f.w;
    }
  }
  __syncthreads();
  const int c=t>>2, rc=t&3;
  u16x8 a,b;
  #pragma unroll
  for(int i=0;i<8;i++) a[i]=f2b(tile[rc*16+i][c]);
  #pragma unroll
  for(int i=0;i<8;i++) b[i]=f2b(tile[rc*16+8+i][c]);
  u16* op = out + (size_t)(c0+c)*R + r0 + rc*16;
  *(u16x8*)op=a; *(u16x8*)(op+8)=b;
}

// --------------- GEMM: A bf16 [M,K] x Bt bf16 [N,K], tile TM x 128 -------------
// MODE=1: fp32 out + bias.
// MODE=2: qkv split. col<1024 -> outQ bf16 row-major (scaled by `scale`).
//         1024..2047 -> outK bf16 packed per-head [b][h][j 2048][d 64].
//         2048..3071 -> outV fp16 packed [b][h][j/32][(j>>2)&3][d 64][(j>>4)&1][j&3].
template<int MODE,int TM>
__global__ __launch_bounds__(256) void gemm_bt_kernel(const u16* __restrict__ A,
    const u16* __restrict__ Bt, u16* __restrict__ outQ, u16* __restrict__ outK,
    u16* __restrict__ outV, float* __restrict__ outF, const float* __restrict__ bias,
    float scale, int M, int N, int K){
  constexpr int MT = TM/32;           // acc m-tiles per wave
  __shared__ u16 As[TM*64];
  __shared__ u16 Bs[128*64];
  const int t=threadIdx.x, w=t>>6, l=t&63, qd=l>>4, ln=l&15;
  const int m0=blockIdx.y*TM, n0=blockIdx.x*128;
  const int wm=(w>>1)*(TM/2), wn=(w&1)*64;
  f32x4 acc[MT][4] = {};
  const int nK = K>>6;
  for(int kt=0; kt<nK; kt++){
    const int k0=kt*64;
    #pragma unroll
    for(int p=0;p<MT;p++){
      const int cid=p*256+t, r=cid>>3, pc=cid&7, g=pc^(r&7);
      gl2lds16(A + (size_t)(m0+r)*K + k0 + g*8, &As[(p*256 + (t&192))*8]);
    }
    #pragma unroll
    for(int p=0;p<4;p++){
      const int cid=p*256+t, r=cid>>3, pc=cid&7, g=pc^(r&7);
      gl2lds16(Bt + (size_t)(n0+r)*K + k0 + g*8, &Bs[(p*256 + (t&192))*8]);
    }
    __syncthreads();
    #pragma unroll
    for(int ks=0;ks<2;ks++){
      u16x8 af[MT], bf[4];
      #pragma unroll
      for(int mt=0;mt<MT;mt++){
        const int m=wm+mt*16+ln, kc=ks*4+qd, pcc=kc^(m&7);
        af[mt]=*(const u16x8*)&As[m*64 + pcc*8];
      }
      #pragma unroll
      for(int nt=0;nt<4;nt++){
        const int n=wn+nt*16+ln, kc=ks*4+qd, pcc=kc^(n&7);
        bf[nt]=*(const u16x8*)&Bs[n*64 + pcc*8];
      }
      #pragma unroll
      for(int mt=0;mt<MT;mt++)
        #pragma unroll
        for(int nt=0;nt<4;nt++)
          acc[mt][nt]=mfma16(af[mt],bf[nt],acc[mt][nt]);
    }
    __syncthreads();
  }
  if(MODE==1){
    #pragma unroll
    for(int mt=0;mt<MT;mt++)
      #pragma unroll
      for(int rr=0;rr<4;rr++){
        const int row = m0+wm+mt*16+qd*4+rr;
        #pragma unroll
        for(int nt=0;nt<4;nt++){
          const int col = n0+wn+nt*16+ln;
          outF[(size_t)row*N+col]=acc[mt][nt][rr]+bias[col];
        }
      }
  } else if(n0<1024){
    #pragma unroll
    for(int mt=0;mt<MT;mt++)
      #pragma unroll
      for(int rr=0;rr<4;rr++){
        const int row = m0+wm+mt*16+qd*4+rr;
        #pragma unroll
        for(int nt=0;nt<4;nt++)
          outQ[(size_t)row*1024 + n0+wn+nt*16+ln]=f2b(acc[mt][nt][rr]*scale);
      }
  } else if(n0<2048){
    // K packed per-head: head is wave-uniform; d = nt*16+ln
    u16* kp = outK + (size_t)((m0>>11)*16 + ((n0-1024+wn)>>6))*131072;
    const int jb = (m0&2047) + wm;
    #pragma unroll
    for(int mt=0;mt<MT;mt++)
      #pragma unroll
      for(int rr=0;rr<4;rr++){
        const int j = jb + mt*16 + qd*4 + rr;
        #pragma unroll
        for(int nt=0;nt<4;nt++)
          kp[(size_t)j*64 + nt*16+ln]=f2b(acc[mt][nt][rr]);
      }
  } else {
    // V packed fp16: lane holds 4 j-consecutive values -> one uint2 per (mt,nt)
    u16* vpp = outV + (size_t)((m0>>11)*16 + ((n0-2048+wn)>>6))*131072;
    const int jb = (m0&2047) + wm;
    #pragma unroll
    for(int mt=0;mt<MT;mt++){
      const int j = jb + mt*16 + qd*4;
      const int vbase = ((j>>5)*4 + ((j>>2)&3))*512 + ((j>>4)&1)*4;
      #pragma unroll
      for(int nt=0;nt<4;nt++){
        const auto lo=__builtin_amdgcn_cvt_pkrtz(acc[mt][nt][0],acc[mt][nt][1]);
        const auto hi=__builtin_amdgcn_cvt_pkrtz(acc[mt][nt][2],acc[mt][nt][3]);
        uint2 w2; w2.x=__builtin_bit_cast(unsigned,lo); w2.y=__builtin_bit_cast(unsigned,hi);
        *(uint2*)&vpp[vbase + (nt*16+ln)*8] = w2;
      }
    }
  }
}

// ------------- flash attention (S^T, fixed-base softmax, BQ=64, i x j wave split) -------------
// Q bf16 [b,2048,1024] (scale*log2e folded), Kp bf16 [b,h,2048,64] packed,
// Vp fp16 [b,h,64,4,64,8] (see gemm epilogue), O bf16 [b,2048,1024].
// 4 waves = (i-half ih, j-half jh2) quadrants: each wave 2 i-tiles x 64 j per 128-j iter.
// DS reads halve vs i-only split (each kf/vf b128 serves 2 i-tiles). Fixed-base softmax
// (no running max) makes the j-half partials combine ADDITIVELY: one LDS merge at end.
__global__ __launch_bounds__(256,4) void attn_kernel(const u16* __restrict__ Q,
    const u16* __restrict__ Kp, const u16* __restrict__ Vp, u16* __restrict__ O){
  __shared__ u16 lds[16384];  // 32KB: Ks=lds[0..8191] (K tile [128 j][64 d], xor swizzle),
                              //       Vs=lds[8192..] (Vp block [4 j32][4 quad][64 d][8])
  u16* Ks = lds;
  u16* Vs = lds+8192;
  const int qt=blockIdx.x, h=blockIdx.y, bb=blockIdx.z;
  const int t=threadIdx.x, w=t>>6, l=t&63, qd=l>>4, ln=l&15;
  const int ih=w&1, jh2=w>>1;
  const int q0=qt*64;
  const size_t baseQ=(size_t)bb*2048*1024 + h*64;
  const size_t baseKV=(size_t)(bb*16+h)*131072;
  u16x8 qf[2][2];
  #pragma unroll
  for(int it=0;it<2;it++)
    #pragma unroll
    for(int ks=0;ks<2;ks++)
      qf[it][ks] = *(const u16x8*)(Q + baseQ + (size_t)(q0+ih*32+it*16+ln)*1024 + ks*32+qd*8);
  f32x2 l2[2]={{0.f,0.f},{0.f,0.f}};
  f32x4 o_acc[2][4]={};
  const f32x4 zf={0.f,0.f,0.f,0.f};

  for(int j0=0;j0<2048;j0+=128){
    __syncthreads();
    #pragma unroll
    for(int p=0;p<4;p++){ // K: 128 rows x 8 chunks of 16B, xor-swizzled packed source
      const int r=(p*256+t)>>3, g=(t&7)^((t>>3)&7);
      gl2lds16(Kp + baseKV + (size_t)(j0+r)*64 + g*8, &Ks[(p*256+(t&192))*8]);
    }
    #pragma unroll
    for(int p=0;p<4;p++){ // Vp: contiguous 16KB block (4 j32 groups)
      gl2lds16(Vp + baseKV + (size_t)(j0>>5)*2048 + (size_t)(p*256+t)*8,
               &Vs[(p*256+(t&192))*8]);
    }
    __syncthreads();

    // S^T for this wave's j-half: s[it][jt], rows j=jh2*64+jt*16+qd*4+rr, cols i=ih*32+it*16+ln
    f32x4 s[2][4];
    #pragma unroll
    for(int ks=0;ks<2;ks++){
      u16x8 kf[4];
      #pragma unroll
      for(int jt=0;jt<4;jt++){
        const int row=jh2*64+jt*16+ln;
        kf[jt]=*(const u16x8*)&Ks[row*64 + (((ks*4+qd)^(ln&7))*8)];
      }
      #pragma unroll
      for(int jt=0;jt<4;jt++){
        if(ks==0){ s[0][jt]=mfma16(kf[jt],qf[0][0],zf); s[1][jt]=mfma16(kf[jt],qf[1][0],zf); }
        else     { s[0][jt]=mfma16(kf[jt],qf[0][1],s[0][jt]); s[1][jt]=mfma16(kf[jt],qf[1][1],s[1][jt]); }
      }
    }
    // P = exp2(s); packed l accumulation; PV direct from regs, b128 V serves 2 j-tiles x 2 i-tiles
    #pragma unroll
    for(int al=0;al<2;al++){
      const int a=jh2*2+al;             // j32 group
      f16x8 vf2[4];
      #pragma unroll
      for(int dt=0;dt<4;dt++)
        vf2[dt]=*(const f16x8*)&Vs[((a*4+qd)*64 + dt*16+ln)*8];
      #pragma unroll
      for(int tt=0;tt<2;tt++){
        const int jt=al*2+tt;
        #pragma unroll
        for(int it=0;it<2;it++){
          const float p0=exp2f(s[it][jt][0]), p1=exp2f(s[it][jt][1]);
          const float p2=exp2f(s[it][jt][2]), p3=exp2f(s[it][jt][3]);
          f32x2 pa; pa.x=p0; pa.y=p1;
          f32x2 pb; pb.x=p2; pb.y=p3;
          l2[it]+=pa+pb;
          const auto lo=__builtin_amdgcn_cvt_pkrtz(p0,p1);
          const auto hi=__builtin_amdgcn_cvt_pkrtz(p2,p3);
          u32x2 pu; pu.x=__builtin_bit_cast(unsigned,lo); pu.y=__builtin_bit_cast(unsigned,hi);
          const f16x4 pf=__builtin_bit_cast(f16x4,pu);
          #pragma unroll
          for(int dt=0;dt<4;dt++){
            const f16x4 vf=tt? __builtin_shufflevector(vf2[dt],vf2[dt],4,5,6,7)
                             : __builtin_shufflevector(vf2[dt],vf2[dt],0,1,2,3);
            o_acc[it][dt]=__builtin_amdgcn_mfma_f32_16x16x16f16(pf,vf,o_acc[it][dt],0,0,0);
          }
        }
      }
    }
  }

  // ---- combine j-halves (additive: fixed-base softmax) ----
  __syncthreads();                       // all LDS tile reads done
  float* cb=(float*)lds;                 // 2 ih x 64 lanes x 36 f32 = 18KB
  if(jh2==1){
    const int base=(ih*64+l)*36;
    #pragma unroll
    for(int it=0;it<2;it++)
      #pragma unroll
      for(int dt=0;dt<4;dt++)
        *(f32x4*)&cb[base+(it*4+dt)*4]=o_acc[it][dt];
    cb[base+32]=l2[0].x+l2[0].y;
    cb[base+33]=l2[1].x+l2[1].y;
  }
  __syncthreads();
  if(jh2==0){
    const int base=(ih*64+l)*36;
    #pragma unroll
    for(int it=0;it<2;it++)
      #pragma unroll
      for(int dt=0;dt<4;dt++)
        o_acc[it][dt]+=*(const f32x4*)&cb[base+(it*4+dt)*4];
    #pragma unroll
    for(int it=0;it<2;it++){
      float li=l2[it].x+l2[it].y + cb[base+32+it];
      li+=__shfl_xor(li,16);
      li+=__shfl_xor(li,32);
      const float linv=1.f/li;
      #pragma unroll
      for(int rr=0;rr<4;rr++){
        const float lr=__shfl(linv,qd*4+rr);
        const int row=q0+ih*32+it*16+qd*4+rr;
        #pragma unroll
        for(int dt=0;dt<4;dt++)
          O[baseQ + (size_t)row*1024 + dt*16+ln]=f2b(o_acc[it][dt][rr]*lr);
      }
    }
  }
}

extern "C" void kernel_launch(void* const* d_in, const int* in_sizes, int n_in,
                              void* d_out, int out_size, void* d_ws, size_t ws_size,
                              hipStream_t stream) {
  const float* x     = (const float*)d_in[0];
  const float* w_q   = (const float*)d_in[1];
  const float* w_kv  = (const float*)d_in[2];
  const float* w_out = (const float*)d_in[3];
  const float* b_out = (const float*)d_in[4];
  const float* gamma = (const float*)d_in[5];
  const float* beta  = (const float*)d_in[6];
  float* out = (float*)d_out;

  char* ws=(char*)d_ws;
  size_t off=0;
  u16* xn    =(u16*)(ws+off); off += (size_t)4096*1024*2;
  u16* wqkvt =(u16*)(ws+off); off += (size_t)3072*1024*2;
  u16* woutt =(u16*)(ws+off); off += (size_t)1024*1024*2;
  u16* qb    =(u16*)(ws+off); off += (size_t)4096*1024*2;
  u16* kpb   =(u16*)(ws+off); off += (size_t)4096*1024*2;
  u16* vpb   =(u16*)(ws+off); off += (size_t)4096*1024*2;
  u16* ob    =(u16*)(ws+off); off += (size_t)4096*1024*2;

  ln_kernel<<<4096,256,0,stream>>>(x,gamma,beta,xn);
  wtrans_all_kernel<<<dim3(64,16),256,0,stream>>>(w_q,w_kv,w_out,wqkvt,woutt);

  const float SCALE_Q = 0.125f*1.4426950408889634f; // 1/sqrt(64) * log2(e)
  gemm_bt_kernel<2,128><<<dim3(24,32),256,0,stream>>>(xn,wqkvt,qb,kpb,vpb,nullptr,nullptr,SCALE_Q,4096,3072,1024);
  attn_kernel<<<dim3(32,16,2),256,0,stream>>>(qb,kpb,vpb,ob);
  gemm_bt_kernel<1,64><<<dim3(8,64),256,0,stream>>>(ob,woutt,nullptr,nullptr,nullptr,out,b_out,1.f,4096,1024,1024);
}